// Round 2
// baseline (648.675 us; speedup 1.0000x reference)
//
#include <hip/hip_runtime.h>
#include <hip/hip_bf16.h>
#include <math.h>

typedef __attribute__((ext_vector_type(8))) short bf16x8;
typedef __attribute__((ext_vector_type(4))) float f32x4;

#define FRAME_PAD (66*66*128)   // padded NHWC frame elems (557568)

#define GLOAD_LDS16(g, l) \
    __builtin_amdgcn_global_load_lds((const __attribute__((address_space(1))) void*)(g), \
                                     (__attribute__((address_space(3))) void*)(l), 16, 0, 0)

__device__ __forceinline__ float sigmoidf_(float x) { return 1.0f / (1.0f + __expf(-x)); }
__device__ __forceinline__ float tanhf_(float x) {
    x = fminf(fmaxf(x, -15.0f), 15.0f);
    float e = __expf(2.0f * x);
    return (e - 1.0f) / (e + 1.0f);
}

// ---------- weights: W[oc][ic][tap] f32 -> Wt[tap][n'][ic] bf16, n' = c*4 + gate ----------
__global__ void wt_kernel(const float* __restrict__ w, __hip_bfloat16* __restrict__ wt)
{
    int idx = blockIdx.x * 256 + threadIdx.x;       // tap*131072 + n*256 + ic
    if (idx >= 9 * 512 * 256) return;
    int ic  = idx & 255;
    int n   = (idx >> 8) & 511;
    int tap = idx >> 17;
    int c = n >> 2, g = n & 3;                       // gate 0:i 1:f 2:o 3:g
    int oc = g * 128 + c;
    wt[idx] = __float2bfloat16(w[((size_t)oc * 256 + (size_t)ic) * 9 + tap]);
}

// ---------- x: NCHW f32 -> padded NHWC bf16 (border pre-zeroed by memset) ----------
__global__ void xpose_kernel(const float* __restrict__ x, __hip_bfloat16* __restrict__ x_pad)
{
    __shared__ float tile[128][65];
    const int f = blockIdx.x >> 6;
    const int y = blockIdx.x & 63;
    const int tid = threadIdx.x;
    const float* src = x + (size_t)f * 524288 + (size_t)y * 64;
    #pragma unroll
    for (int it = 0; it < 32; ++it) {
        int c  = it * 4 + (tid >> 6);
        int xc = tid & 63;
        tile[c][xc] = src[(size_t)c * 4096 + xc];
    }
    __syncthreads();
    __hip_bfloat16* dst = x_pad + (size_t)f * FRAME_PAD + (size_t)((y + 1) * 66 + 1) * 128;
    #pragma unroll
    for (int it = 0; it < 16; ++it) {
        int xr = it * 4 + (tid >> 6);
        int c2 = (tid & 63) * 2;
        __hip_bfloat162 v;
        v.x = __float2bfloat16(tile[c2][xr]);
        v.y = __float2bfloat16(tile[c2 + 1][xr]);
        *(__hip_bfloat162*)(dst + (size_t)xr * 128 + c2) = v;
    }
}

// ---------- fused transposed implicit-GEMM conv + LSTM gates ----------
// D[n'][m]: n' = c*4+gate (512), m = b*4096 + y*64 + x (16384), K = tap*256 + ic (2304).
// First MFMA operand = weight rows (n'), second = spatial rows (m); C/D layout puts the
// 4 gates of channel c in one lane's reg quad -> pointwise LSTM in-register, no z buffer.
__global__ __launch_bounds__(256)
void conv_gemm(const __hip_bfloat16* __restrict__ x_pad,
               const __hip_bfloat16* __restrict__ h_pad,
               const __hip_bfloat16* __restrict__ wt,
               const float* __restrict__ bias,
               float* __restrict__ c_state, int t)
{
    __shared__ alignas(16) __hip_bfloat16 W_s[2][128 * 32];
    __shared__ alignas(16) __hip_bfloat16 S_s[2][128 * 32];
    const int tid  = threadIdx.x;
    const int wv   = tid >> 6;
    const int lane = tid & 63;

    // XCD-chunked tile remap: 4 n-blocks sharing a spatial panel land on one XCD.
    const int F    = blockIdx.x;
    const int tile = ((F & 7) << 6) + (F >> 3);
    const int n0   = (tile & 3) * 128;
    const int mblk = tile >> 2;
    const int b    = mblk >> 5;
    const int y0   = (mblk & 31) * 2;
    const int m0   = mblk * 128;

    const __hip_bfloat16* xf = x_pad + (size_t)(b * 8 + t) * FRAME_PAD;
    const __hip_bfloat16* hf = h_pad + (size_t)(b * 9 + t) * FRAME_PAD;

    // staging offsets (global source pre-swizzled: q_src = q ^ ((row>>1)&3))
    int offW[2], offS[2];
    #pragma unroll
    for (int i = 0; i < 2; ++i) {
        int slot = i * 256 + tid;
        int row  = slot >> 2;
        int qs   = (slot & 3) ^ ((row >> 1) & 3);
        offS[i] = ((y0 + (row >> 6)) * 66 + (row & 63)) * 128 + qs * 8;
        offW[i] = (n0 + row) * 256 + qs * 8;
    }

    f32x4 acc[4][4] = {};
    const int wr = wv >> 1, wc = wv & 1;
    const int fr = lane & 15, fq = lane >> 4;
    const int fqs   = fq ^ ((fr >> 1) & 3);          // swizzled read slot (lane-constant)
    const int wRow0 = (wr * 64 + fr) * 32 + fqs * 8;
    const int sRow0 = (wc * 64 + fr) * 32 + fqs * 8;

    auto STAGE = [&](int bb, int kk) {
        const int tap  = kk >> 3;
        const int koff = (kk & 7) * 32;
        const int dy = tap / 3, dx = tap % 3;
        const __hip_bfloat16* src;
        int ch;
        if (koff < 128) { src = xf; ch = koff; }
        else            { src = hf; ch = koff - 128; }
        const int adds = (dy * 66 + dx) * 128 + ch;
        const int addw = tap * 131072 + koff;
        #pragma unroll
        for (int i = 0; i < 2; ++i) GLOAD_LDS16(src + adds + offS[i], &S_s[bb][(i * 256 + tid) * 8]);
        #pragma unroll
        for (int i = 0; i < 2; ++i) GLOAD_LDS16(wt + addw + offW[i], &W_s[bb][(i * 256 + tid) * 8]);
    };

    auto COMPUTE = [&](int bb) {
        const __hip_bfloat16* Wb = &W_s[bb][0];
        const __hip_bfloat16* Sb = &S_s[bb][0];
        bf16x8 w[4], s[4];
        #pragma unroll
        for (int ri = 0; ri < 4; ++ri) w[ri] = *(const bf16x8*)(Wb + wRow0 + ri * 512);
        #pragma unroll
        for (int ci = 0; ci < 4; ++ci) s[ci] = *(const bf16x8*)(Sb + sRow0 + ci * 512);
        #pragma unroll
        for (int ri = 0; ri < 4; ++ri)
            #pragma unroll
            for (int ci = 0; ci < 4; ++ci)
                acc[ri][ci] = __builtin_amdgcn_mfma_f32_16x16x32_bf16(w[ri], s[ci], acc[ri][ci], 0, 0, 0);
    };

    int buf = 0;
    STAGE(0, 0);
    __syncthreads();
    for (int kk = 0; kk < 71; ++kk) {
        STAGE(buf ^ 1, kk + 1);     // next-tile loads in flight during compute
        COMPUTE(buf);
        __syncthreads();            // vmcnt(0)+lgkmcnt(0)+barrier
        buf ^= 1;
    }
    COMPUTE(buf);

    // ---------- fused LSTM gate epilogue ----------
    const int c0    = (n0 >> 2) + wr * 16;
    const int mcol0 = m0 + wc * 64 + fr;
    __hip_bfloat16* hout = (__hip_bfloat16*)h_pad + (size_t)(b * 9 + t + 1) * FRAME_PAD;
    #pragma unroll
    for (int ri = 0; ri < 4; ++ri) {
        const int c = c0 + ri * 4 + fq;
        const float bi  = bias[c];
        const float bfv = bias[128 + c];
        const float bo  = bias[256 + c];
        const float bg  = bias[384 + c];
        float* csrow = c_state + (size_t)c * 16384;
        #pragma unroll
        for (int ci = 0; ci < 4; ++ci) {
            const int m = mcol0 + ci * 16;
            const int s = m & 4095;
            const float cold = csrow[m];
            const float zi = acc[ri][ci][0] + bi;
            const float zf = acc[ri][ci][1] + bfv;
            const float zo = acc[ri][ci][2] + bo;
            const float zg = acc[ri][ci][3] + bg;
            const float cn = sigmoidf_(zf) * cold + sigmoidf_(zi) * tanhf_(zg);
            const float h  = sigmoidf_(zo) * tanhf_(cn);
            csrow[m] = cn;
            hout[(size_t)(((s >> 6) + 1) * 66 + (s & 63) + 1) * 128 + c] = __float2bfloat16(h);
        }
    }
}

// ---------- final: padded-NHWC bf16 h -> NCHW f32 out with BN(eval)+ReLU ----------
__global__ void bn_out_kernel(const __hip_bfloat16* __restrict__ h_pad,
                              const float* __restrict__ gamma, const float* __restrict__ beta,
                              const float* __restrict__ rmean, const float* __restrict__ rvar,
                              float* __restrict__ out)
{
    __shared__ float tile[64][130];
    __shared__ float sc_s[128], sh_s[128];
    const int fo  = blockIdx.x >> 6;
    const int y   = blockIdx.x & 63;
    const int tid = threadIdx.x;
    if (tid < 128) {
        float sc = gamma[tid] * rsqrtf(rvar[tid] + 1e-5f);
        sc_s[tid] = sc;
        sh_s[tid] = beta[tid] - rmean[tid] * sc;
    }
    const int b = fo >> 3, t = fo & 7;
    const __hip_bfloat16* src =
        h_pad + (size_t)(b * 9 + 1 + t) * FRAME_PAD + (size_t)((y + 1) * 66 + 1) * 128;
    #pragma unroll
    for (int it = 0; it < 32; ++it) {
        int xr = it * 2 + (tid >> 7);
        int c  = tid & 127;
        tile[xr][c] = __bfloat162float(src[(size_t)xr * 128 + c]);
    }
    __syncthreads();
    float* dst = out + (size_t)fo * 524288 + (size_t)y * 64;
    #pragma unroll
    for (int it = 0; it < 32; ++it) {
        int c  = it * 4 + (tid >> 6);
        int xc = tid & 63;
        float v = tile[xc][c] * sc_s[c] + sh_s[c];
        dst[(size_t)c * 4096 + xc] = fmaxf(v, 0.0f);
    }
}

extern "C" void kernel_launch(void* const* d_in, const int* in_sizes, int n_in,
                              void* d_out, int out_size, void* d_ws, size_t ws_size,
                              hipStream_t stream)
{
    const float* x      = (const float*)d_in[0];
    const float* w_conv = (const float*)d_in[1];
    const float* b_conv = (const float*)d_in[2];
    const float* gamma  = (const float*)d_in[3];
    const float* beta   = (const float*)d_in[4];
    const float* rmean  = (const float*)d_in[5];
    const float* rvar   = (const float*)d_in[6];
    float* out = (float*)d_out;

    // workspace layout (bytes)
    //   Wt      @ 0          : 9*512*256*2    = 2,359,296
    //   x_pad   @ 2359296    : 32*66*66*128*2 = 35,684,352
    //   h_pad   @ 38043648   : 36*66*66*128*2 = 40,144,896  (slot b*9+0 = zeros)
    //   c_state @ 78188544   : 128*16384*4    = 8,388,608   ([c][m] layout)
    //   total 86,577,152
    if (ws_size < 86577152u) return;

    char* ws = (char*)d_ws;
    __hip_bfloat16* Wt    = (__hip_bfloat16*)(ws);
    __hip_bfloat16* x_pad = (__hip_bfloat16*)(ws + 2359296);
    __hip_bfloat16* h_pad = (__hip_bfloat16*)(ws + 38043648);
    float* c_state        = (float*)(ws + 78188544);

    hipMemsetAsync(x_pad, 0, 35684352, stream);
    hipMemsetAsync(h_pad, 0, 40144896, stream);
    hipMemsetAsync(c_state, 0, 8388608, stream);

    wt_kernel<<<4608, 256, 0, stream>>>(w_conv, Wt);
    xpose_kernel<<<2048, 256, 0, stream>>>(x, x_pad);

    for (int t = 0; t < 8; ++t) {
        conv_gemm<<<512, 256, 0, stream>>>(x_pad, h_pad, Wt, b_conv, c_state, t);
    }
    bn_out_kernel<<<2048, 256, 0, stream>>>(h_pad, gamma, beta, rmean, rvar, out);
}

// Round 3
// 403.417 us; speedup vs baseline: 1.6080x; 1.6080x over previous
//
#include <hip/hip_runtime.h>
#include <hip/hip_bf16.h>
#include <math.h>

typedef __attribute__((ext_vector_type(8))) short bf16x8;
typedef __attribute__((ext_vector_type(4))) float f32x4;

#define FRAME_PAD (66*66*128)   // padded NHWC frame elems (557568)

#define GLOAD_LDS16(g, l) \
    __builtin_amdgcn_global_load_lds((const __attribute__((address_space(1))) void*)(g), \
                                     (__attribute__((address_space(3))) void*)(l), 16, 0, 0)

#define WAITV6    asm volatile("s_waitcnt vmcnt(6)" ::: "memory")
#define WAITV0    asm volatile("s_waitcnt vmcnt(0)" ::: "memory")
#define WAITLGKM0 asm volatile("s_waitcnt lgkmcnt(0)" ::: "memory")
#define SBAR      __builtin_amdgcn_s_barrier()

__device__ __forceinline__ float sigmoidf_(float x) { return 1.0f / (1.0f + __expf(-x)); }
__device__ __forceinline__ float tanhf_(float x) {
    x = fminf(fmaxf(x, -15.0f), 15.0f);
    float e = __expf(2.0f * x);
    return (e - 1.0f) / (e + 1.0f);
}

// ---------- weights: W[oc][ic][tap] f32 -> Wt[tap][n'][ic] bf16, n' = c*4 + gate ----------
__global__ void wt_kernel(const float* __restrict__ w, __hip_bfloat16* __restrict__ wt)
{
    int idx = blockIdx.x * 256 + threadIdx.x;       // tap*131072 + n*256 + ic
    if (idx >= 9 * 512 * 256) return;
    int ic  = idx & 255;
    int n   = (idx >> 8) & 511;
    int tap = idx >> 17;
    int c = n >> 2, g = n & 3;                       // gate 0:i 1:f 2:o 3:g
    int oc = g * 128 + c;
    wt[idx] = __float2bfloat16(w[((size_t)oc * 256 + (size_t)ic) * 9 + tap]);
}

// ---------- x: NCHW f32 -> padded NHWC bf16 (border pre-zeroed by memset) ----------
__global__ void xpose_kernel(const float* __restrict__ x, __hip_bfloat16* __restrict__ x_pad)
{
    __shared__ float tile[128][65];
    const int f = blockIdx.x >> 6;
    const int y = blockIdx.x & 63;
    const int tid = threadIdx.x;
    const float* src = x + (size_t)f * 524288 + (size_t)y * 64;
    #pragma unroll
    for (int it = 0; it < 32; ++it) {
        int c  = it * 4 + (tid >> 6);
        int xc = tid & 63;
        tile[c][xc] = src[(size_t)c * 4096 + xc];
    }
    __syncthreads();
    __hip_bfloat16* dst = x_pad + (size_t)f * FRAME_PAD + (size_t)((y + 1) * 66 + 1) * 128;
    #pragma unroll
    for (int it = 0; it < 16; ++it) {
        int xr = it * 4 + (tid >> 6);
        int c2 = (tid & 63) * 2;
        __hip_bfloat162 v;
        v.x = __float2bfloat16(tile[c2][xr]);
        v.y = __float2bfloat16(tile[c2 + 1][xr]);
        *(__hip_bfloat162*)(dst + (size_t)xr * 128 + c2) = v;
    }
}

// ---------- fused conv-GEMM + LSTM gates, counted-vmcnt pipeline ----------
// D[n'][m]: n' = c*4+gate (512, tile BN=128), m = spatial (16384, tile BM=256).
// K = tap*256 + ic (2304) in 36 tiles of BK=64. Depth-2 prefetch, vmcnt(6) steady state.
// 8 waves as 4(m) x 2(n); per-wave 64x64 output = acc[4][4] of 16x16x32 MFMA.
__global__ __launch_bounds__(512, 2)
void conv_gemm(const __hip_bfloat16* __restrict__ x_pad,
               const __hip_bfloat16* __restrict__ h_pad,
               const __hip_bfloat16* __restrict__ wt,
               const float* __restrict__ bias,
               float* __restrict__ c_state, int t)
{
    __shared__ alignas(16) __hip_bfloat16 S_s[2][256 * 64];   // spatial tiles, 2x32KB
    __shared__ alignas(16) __hip_bfloat16 W_s[2][128 * 64];   // weight tiles,  2x16KB
    const int tid  = threadIdx.x;
    const int wv   = tid >> 6;
    const int lane = tid & 63;

    // XCD-chunked remap: each XCD owns 8 consecutive m-panels x all 4 n-blocks.
    const int F    = blockIdx.x;                 // 256 blocks
    const int tile = (F >> 3) + (F & 7) * 32;
    const int n0   = (tile & 3) * 128;
    const int mblk = tile >> 2;                  // 0..63, 256 spatial rows each
    const int b    = mblk >> 4;
    const int y0   = (mblk & 15) * 4;
    const int m0   = mblk * 256;

    const __hip_bfloat16* xf = x_pad + (size_t)(b * 8 + t) * FRAME_PAD;
    const __hip_bfloat16* hf = h_pad + (size_t)(b * 9 + t) * FRAME_PAD;

    // per-thread staging offsets (source pre-swizzled: q_src = q ^ (row&7), involution)
    int aOff[4], bOff[2];
    #pragma unroll
    for (int j = 0; j < 4; ++j) {
        int sid = j * 512 + tid;
        int row = sid >> 3;
        int q   = (sid & 7) ^ (row & 7);
        aOff[j] = ((y0 + (row >> 6)) * 66 + (row & 63)) * 128 + q * 8;
    }
    #pragma unroll
    for (int j = 0; j < 2; ++j) {
        int sid = j * 512 + tid;
        int row = sid >> 3;
        int q   = (sid & 7) ^ (row & 7);
        bOff[j] = (n0 + row) * 256 + q * 8;
    }

    auto STAGE = [&](__hip_bfloat16* Sl, __hip_bfloat16* Wl, int kt) {
        const int tap = kt >> 2;
        const int icq = (kt & 3) * 64;
        const int dy = tap / 3, dx = tap % 3;
        const __hip_bfloat16* asrc =
            (icq < 128 ? xf + icq : hf + (icq - 128)) + (dy * 66 + dx) * 128;
        #pragma unroll
        for (int j = 0; j < 4; ++j)
            GLOAD_LDS16(asrc + aOff[j], Sl + (size_t)(j * 512 + tid) * 8);
        const __hip_bfloat16* bsrc = wt + tap * 131072 + icq;
        #pragma unroll
        for (int j = 0; j < 2; ++j)
            GLOAD_LDS16(bsrc + bOff[j], Wl + (size_t)(j * 512 + tid) * 8);
    };

    // fragment read offsets (swizzled, lane-constant); kh=1 is XOR 32 elems (64B)
    const int wm = wv >> 1, wn = wv & 1;
    const int fr = lane & 15, fq = lane >> 4;
    const int slot = (fq ^ (fr & 7)) * 8;
    const int sOff0 = (wm * 64 + fr) * 64 + slot, sOff1 = sOff0 ^ 32;
    const int wOff0 = (wn * 64 + fr) * 64 + slot, wOff1 = wOff0 ^ 32;

    f32x4 acc[4][4] = {};

    auto ITER = [&](__hip_bfloat16* Sb, __hip_bfloat16* Wb, int kt) {
        if (kt < 35) { WAITV6; } else { WAITV0; }   // current tile landed; next stays in flight
        SBAR;
        bf16x8 w0[4], w1[4], s0[4], s1[4];
        #pragma unroll
        for (int ri = 0; ri < 4; ++ri) {
            w0[ri] = *(const bf16x8*)(Wb + wOff0 + ri * 1024);
            w1[ri] = *(const bf16x8*)(Wb + wOff1 + ri * 1024);
        }
        #pragma unroll
        for (int ci = 0; ci < 4; ++ci) {
            s0[ci] = *(const bf16x8*)(Sb + sOff0 + ci * 1024);
            s1[ci] = *(const bf16x8*)(Sb + sOff1 + ci * 1024);
        }
        __builtin_amdgcn_s_setprio(1);
        #pragma unroll
        for (int ri = 0; ri < 4; ++ri)
            #pragma unroll
            for (int ci = 0; ci < 4; ++ci)
                acc[ri][ci] = __builtin_amdgcn_mfma_f32_16x16x32_bf16(w0[ri], s0[ci], acc[ri][ci], 0, 0, 0);
        __builtin_amdgcn_s_setprio(0);
        WAITLGKM0;                               // all 16 reads hardware-complete
        __builtin_amdgcn_sched_barrier(0);       // rule 18: pin the boundary
        SBAR;                                    // all waves done reading this buffer
        if (kt < 34) STAGE(Sb, Wb, kt + 2);      // overwrite now safe; loads fly ahead
        __builtin_amdgcn_s_setprio(1);
        #pragma unroll
        for (int ri = 0; ri < 4; ++ri)
            #pragma unroll
            for (int ci = 0; ci < 4; ++ci)
                acc[ri][ci] = __builtin_amdgcn_mfma_f32_16x16x32_bf16(w1[ri], s1[ci], acc[ri][ci], 0, 0, 0);
        __builtin_amdgcn_s_setprio(0);
    };

    STAGE(S_s[0], W_s[0], 0);
    STAGE(S_s[1], W_s[1], 1);                    // 12 loads/thread in flight
    #pragma unroll 1
    for (int kt = 0; kt < 36; kt += 2) {
        ITER(S_s[0], W_s[0], kt);
        ITER(S_s[1], W_s[1], kt + 1);
    }

    // ---------- fused LSTM gate epilogue (identical math to validated round 2) ----------
    const int c0    = (n0 >> 2) + wn * 16;
    const int mcol0 = m0 + wm * 64 + fr;
    __hip_bfloat16* hout = (__hip_bfloat16*)h_pad + (size_t)(b * 9 + t + 1) * FRAME_PAD;
    #pragma unroll
    for (int ri = 0; ri < 4; ++ri) {
        const int c = c0 + ri * 4 + fq;
        const float bi  = bias[c];
        const float bfv = bias[128 + c];
        const float bo  = bias[256 + c];
        const float bg  = bias[384 + c];
        float* csrow = c_state + (size_t)c * 16384;
        #pragma unroll
        for (int ci = 0; ci < 4; ++ci) {
            const int m = mcol0 + ci * 16;
            const int s = m & 4095;
            const float cold = csrow[m];
            const float zi = acc[ri][ci][0] + bi;
            const float zf = acc[ri][ci][1] + bfv;
            const float zo = acc[ri][ci][2] + bo;
            const float zg = acc[ri][ci][3] + bg;
            const float cn = sigmoidf_(zf) * cold + sigmoidf_(zi) * tanhf_(zg);
            const float h  = sigmoidf_(zo) * tanhf_(cn);
            csrow[m] = cn;
            hout[(size_t)(((s >> 6) + 1) * 66 + (s & 63) + 1) * 128 + c] = __float2bfloat16(h);
        }
    }
}

// ---------- final: padded-NHWC bf16 h -> NCHW f32 out with BN(eval)+ReLU ----------
__global__ void bn_out_kernel(const __hip_bfloat16* __restrict__ h_pad,
                              const float* __restrict__ gamma, const float* __restrict__ beta,
                              const float* __restrict__ rmean, const float* __restrict__ rvar,
                              float* __restrict__ out)
{
    __shared__ float tile[64][130];
    __shared__ float sc_s[128], sh_s[128];
    const int fo  = blockIdx.x >> 6;
    const int y   = blockIdx.x & 63;
    const int tid = threadIdx.x;
    if (tid < 128) {
        float sc = gamma[tid] * rsqrtf(rvar[tid] + 1e-5f);
        sc_s[tid] = sc;
        sh_s[tid] = beta[tid] - rmean[tid] * sc;
    }
    const int b = fo >> 3, t = fo & 7;
    const __hip_bfloat16* src =
        h_pad + (size_t)(b * 9 + 1 + t) * FRAME_PAD + (size_t)((y + 1) * 66 + 1) * 128;
    #pragma unroll
    for (int it = 0; it < 32; ++it) {
        int xr = it * 2 + (tid >> 7);
        int c  = tid & 127;
        tile[xr][c] = __bfloat162float(src[(size_t)xr * 128 + c]);
    }
    __syncthreads();
    float* dst = out + (size_t)fo * 524288 + (size_t)y * 64;
    #pragma unroll
    for (int it = 0; it < 32; ++it) {
        int c  = it * 4 + (tid >> 6);
        int xc = tid & 63;
        float v = tile[xc][c] * sc_s[c] + sh_s[c];
        dst[(size_t)c * 4096 + xc] = fmaxf(v, 0.0f);
    }
}

extern "C" void kernel_launch(void* const* d_in, const int* in_sizes, int n_in,
                              void* d_out, int out_size, void* d_ws, size_t ws_size,
                              hipStream_t stream)
{
    const float* x      = (const float*)d_in[0];
    const float* w_conv = (const float*)d_in[1];
    const float* b_conv = (const float*)d_in[2];
    const float* gamma  = (const float*)d_in[3];
    const float* beta   = (const float*)d_in[4];
    const float* rmean  = (const float*)d_in[5];
    const float* rvar   = (const float*)d_in[6];
    float* out = (float*)d_out;

    // workspace layout (bytes)
    //   Wt      @ 0          : 9*512*256*2    = 2,359,296
    //   x_pad   @ 2359296    : 32*66*66*128*2 = 35,684,352
    //   h_pad   @ 38043648   : 36*66*66*128*2 = 40,144,896  (slot b*9+0 = zeros)
    //   c_state @ 78188544   : 128*16384*4    = 8,388,608   ([c][m] layout)
    //   total 86,577,152
    if (ws_size < 86577152u) return;

    char* ws = (char*)d_ws;
    __hip_bfloat16* Wt    = (__hip_bfloat16*)(ws);
    __hip_bfloat16* x_pad = (__hip_bfloat16*)(ws + 2359296);
    __hip_bfloat16* h_pad = (__hip_bfloat16*)(ws + 38043648);
    float* c_state        = (float*)(ws + 78188544);

    hipMemsetAsync(x_pad, 0, 35684352, stream);
    hipMemsetAsync(h_pad, 0, 40144896, stream);
    hipMemsetAsync(c_state, 0, 8388608, stream);

    wt_kernel<<<4608, 256, 0, stream>>>(w_conv, Wt);
    xpose_kernel<<<2048, 256, 0, stream>>>(x, x_pad);

    for (int t = 0; t < 8; ++t) {
        conv_gemm<<<256, 512, 0, stream>>>(x_pad, h_pad, Wt, b_conv, c_state, t);
    }
    bn_out_kernel<<<2048, 256, 0, stream>>>(h_pad, gamma, beta, rmean, rvar, out);
}

// Round 4
// 382.106 us; speedup vs baseline: 1.6976x; 1.0558x over previous
//
#include <hip/hip_runtime.h>
#include <hip/hip_bf16.h>
#include <math.h>

typedef __attribute__((ext_vector_type(8))) short bf16x8;
typedef __attribute__((ext_vector_type(4))) float f32x4;

#define FRAME_PAD (66*66*128)   // padded NHWC frame elems (557568)

#define GLOAD_LDS16(g, l) \
    __builtin_amdgcn_global_load_lds((const __attribute__((address_space(1))) void*)(g), \
                                     (__attribute__((address_space(3))) void*)(l), 16, 0, 0)

#define WAITV6    asm volatile("s_waitcnt vmcnt(6)" ::: "memory")
#define WAITV0    asm volatile("s_waitcnt vmcnt(0)" ::: "memory")
#define WAITLGKM0 asm volatile("s_waitcnt lgkmcnt(0)" ::: "memory")
#define SBAR      __builtin_amdgcn_s_barrier()

__device__ __forceinline__ float sigmoidf_(float x) { return 1.0f / (1.0f + __expf(-x)); }
__device__ __forceinline__ float tanhf_(float x) {
    x = fminf(fmaxf(x, -15.0f), 15.0f);
    float e = __expf(2.0f * x);
    return (e - 1.0f) / (e + 1.0f);
}
__device__ __forceinline__ float b2f_(short u) {
    unsigned int v = ((unsigned int)(unsigned short)u) << 16;
    return __builtin_bit_cast(float, v);
}
__device__ __forceinline__ short f2b_(float f) {
    __hip_bfloat16 hb = __float2bfloat16(f);
    return *reinterpret_cast<short*>(&hb);
}

// ---------- weights: W[oc][ic][tap] f32 -> Wt[tap][n'][ic] bf16, n' = c*4 + gate ----------
__global__ void wt_kernel(const float* __restrict__ w, __hip_bfloat16* __restrict__ wt)
{
    int idx = blockIdx.x * 256 + threadIdx.x;       // tap*131072 + n*256 + ic
    if (idx >= 9 * 512 * 256) return;
    int ic  = idx & 255;
    int n   = (idx >> 8) & 511;
    int tap = idx >> 17;
    int c = n >> 2, g = n & 3;                       // gate 0:i 1:f 2:o 3:g
    int oc = g * 128 + c;
    wt[idx] = __float2bfloat16(w[((size_t)oc * 256 + (size_t)ic) * 9 + tap]);
}

// ---------- zero the pad borders of all x and h frames (replaces 84MB memsets) ----------
__global__ void border_kernel(__hip_bfloat16* __restrict__ x_pad,
                              __hip_bfloat16* __restrict__ h_pad)
{
    const int fr = blockIdx.x;                        // 0..31 x, 32..63 h
    __hip_bfloat16* base = (fr < 32) ? x_pad + (size_t)fr * FRAME_PAD
                                     : h_pad + (size_t)(fr - 32) * FRAME_PAD;
    bf16x8 z = {};
    // rows y=0 and y=65: 2 x 8448 elems = 2112 chunks of 8
    for (int u = threadIdx.x; u < 2112; u += 256) {
        int half = (u >= 1056) ? 1 : 0;
        int v = u - half * 1056;
        *(bf16x8*)(base + (size_t)(half * 65 * 66) * 128 + (size_t)v * 8) = z;
    }
    // cols x=0,65 for y=1..64: 64*2*16 = 2048 chunks of 8
    for (int u = threadIdx.x; u < 2048; u += 256) {
        int yy = 1 + (u >> 5);
        int r = u & 31;
        int side = r >> 4, c16 = r & 15;
        *(bf16x8*)(base + (size_t)(yy * 66 + side * 65) * 128 + (size_t)c16 * 8) = z;
    }
}

// ---------- x: NCHW f32 -> padded NHWC bf16 (vectorized, LDS stride-129 transpose) ----------
__global__ void xpose_kernel(const float* __restrict__ x, __hip_bfloat16* __restrict__ x_pad)
{
    __shared__ float tile[64][129];                  // [x][c]
    const int f = blockIdx.x >> 6;
    const int y = blockIdx.x & 63;
    const int tid = threadIdx.x;
    const float* src = x + (size_t)f * 524288 + (size_t)y * 64;
    #pragma unroll
    for (int it = 0; it < 8; ++it) {                 // 128 c x 16 xq / 256 thr
        int c  = it * 16 + (tid >> 4);
        int xq = tid & 15;
        float4 v = *(const float4*)(src + (size_t)c * 4096 + xq * 4);
        tile[xq * 4 + 0][c] = v.x;
        tile[xq * 4 + 1][c] = v.y;
        tile[xq * 4 + 2][c] = v.z;
        tile[xq * 4 + 3][c] = v.w;
    }
    __syncthreads();
    __hip_bfloat16* dst = x_pad + (size_t)f * FRAME_PAD + (size_t)((y + 1) * 66 + 1) * 128;
    const int g = tid & 15;
    #pragma unroll
    for (int it = 0; it < 4; ++it) {                 // 64 x-rows x 16 g / 256 thr
        int xr = it * 16 + (tid >> 4);
        bf16x8 o;
        #pragma unroll
        for (int e = 0; e < 8; ++e) o[e] = f2b_(tile[xr][g * 8 + e]);
        *(bf16x8*)(dst + (size_t)xr * 128 + g * 8) = o;
    }
}

// ---------- fused conv-GEMM + LSTM gates; 3-slot A-ring, fine 2-phase/kt pipeline ----------
// D[n'][m]: n' = c*4+gate (512, BN=128), m = spatial (16384, BM=256).
// K tiles of BK=64: T0 -> 18 tiles (x only, h==0), else 36. vmcnt(6) steady state.
template<bool T0>
__global__ __launch_bounds__(512, 2)
void conv_gemm(const __hip_bfloat16* __restrict__ x_pad,
               const __hip_bfloat16* __restrict__ h_pad,
               const __hip_bfloat16* __restrict__ wt,
               const float* __restrict__ bias,
               float* __restrict__ c_state, int t)
{
    __shared__ alignas(16) __hip_bfloat16 S_s[3][256 * 64];   // spatial ring, 3x32KB
    __shared__ alignas(16) __hip_bfloat16 W_s[2][128 * 64];   // weight dbuf,  2x16KB
    const int tid  = threadIdx.x;
    const int wv   = tid >> 6;
    const int lane = tid & 63;
    const int KT   = T0 ? 18 : 36;

    // XCD-chunked remap: each XCD owns 8 consecutive m-panels x all 4 n-blocks.
    const int F    = blockIdx.x;                 // 256 blocks
    const int tile = (F >> 3) + (F & 7) * 32;
    const int n0   = (tile & 3) * 128;
    const int mblk = tile >> 2;                  // 0..63
    const int b    = mblk >> 4;
    const int y0   = (mblk & 15) * 4;
    const int m0   = mblk * 256;

    const __hip_bfloat16* xf = x_pad + (size_t)(b * 8 + t) * FRAME_PAD;
    const __hip_bfloat16* hf = h_pad + (size_t)(b * 8 + (T0 ? 0 : t - 1)) * FRAME_PAD;

    // per-thread staging offsets (source pre-swizzled: q_src = q ^ (row&7), involution)
    int aOff[4], bOff[2];
    #pragma unroll
    for (int j = 0; j < 4; ++j) {
        int sid = j * 512 + tid;
        int row = sid >> 3;
        int q   = (sid & 7) ^ (row & 7);
        aOff[j] = ((y0 + (row >> 6)) * 66 + (row & 63)) * 128 + q * 8;
    }
    #pragma unroll
    for (int j = 0; j < 2; ++j) {
        int sid = j * 512 + tid;
        int row = sid >> 3;
        int q   = (sid & 7) ^ (row & 7);
        bOff[j] = (n0 + row) * 256 + q * 8;
    }

    auto stageA = [&](__hip_bfloat16* Sl, int kt, int j0, int j1) {
        int tap, icq;
        const __hip_bfloat16* sb;
        if constexpr (T0) { tap = kt >> 1; icq = (kt & 1) * 64; sb = xf + icq; }
        else { tap = kt >> 2; icq = (kt & 3) * 64;
               sb = (icq < 128) ? (xf + icq) : (hf + (icq - 128)); }
        const int dy = tap / 3, dx = tap % 3;
        const __hip_bfloat16* a = sb + (dy * 66 + dx) * 128;
        for (int j = j0; j < j1; ++j)
            GLOAD_LDS16(a + aOff[j], Sl + (size_t)(j * 512 + tid) * 8);
    };
    auto stageW = [&](__hip_bfloat16* Wl, int kt) {
        int tap, icq;
        if constexpr (T0) { tap = kt >> 1; icq = (kt & 1) * 64; }
        else { tap = kt >> 2; icq = (kt & 3) * 64; }
        const __hip_bfloat16* bsrc = wt + tap * 131072 + icq;
        #pragma unroll
        for (int j = 0; j < 2; ++j)
            GLOAD_LDS16(bsrc + bOff[j], Wl + (size_t)(j * 512 + tid) * 8);
    };

    // fragment read offsets (swizzled, lane-constant); K-half 1 = XOR 32 elems (64B)
    const int wm = wv >> 1, wn = wv & 1;
    const int fr = lane & 15, fq = lane >> 4;
    const int slot = (fq ^ (fr & 7)) * 8;
    const int sOff0 = (wm * 64 + fr) * 64 + slot, sOff1 = sOff0 ^ 32;
    const int wOff0 = (wn * 64 + fr) * 64 + slot, wOff1 = wOff0 ^ 32;

    f32x4 acc[4][4] = {};

    __hip_bfloat16 *Sr = &S_s[0][0], *Sn = &S_s[1][0], *Sf = &S_s[2][0];
    __hip_bfloat16 *Wr = &W_s[0][0], *Wn = &W_s[1][0];

    stageA(Sr, 0, 0, 4); stageW(Wr, 0);
    stageA(Sn, 1, 0, 4); stageW(Wn, 1);
    WAITV6;                                      // tile 0 landed; tile 1 in flight
    SBAR;

    #pragma unroll 1
    for (int kt = 0; kt < KT; ++kt) {
        bf16x8 w0[4], w1[4], s0[4], s1[4];
        // ---- phase 0: all W frags + s0 ; stage A-half of kt+2 into ring slot ----
        #pragma unroll
        for (int ri = 0; ri < 4; ++ri) w0[ri] = *(const bf16x8*)(Wr + wOff0 + ri * 1024);
        #pragma unroll
        for (int ci = 0; ci < 4; ++ci) s0[ci] = *(const bf16x8*)(Sr + sOff0 + ci * 1024);
        #pragma unroll
        for (int ri = 0; ri < 4; ++ri) w1[ri] = *(const bf16x8*)(Wr + wOff1 + ri * 1024);
        if (kt < KT - 2) stageA(Sf, kt + 2, 0, 2);
        SBAR;
        WAITLGKM0;
        __builtin_amdgcn_s_setprio(1);
        #pragma unroll
        for (int ri = 0; ri < 4; ++ri)
            #pragma unroll
            for (int ci = 0; ci < 4; ++ci)
                acc[ri][ci] = __builtin_amdgcn_mfma_f32_16x16x32_bf16(w0[ri], s0[ci], acc[ri][ci], 0, 0, 0);
        __builtin_amdgcn_s_setprio(0);
        SBAR;                                    // all waves done with Wr reads
        // ---- phase 1: s1 ; stage A-half2 + W of kt+2 (W into Wr: safe post-barrier) ----
        #pragma unroll
        for (int ci = 0; ci < 4; ++ci) s1[ci] = *(const bf16x8*)(Sr + sOff1 + ci * 1024);
        if (kt < KT - 2) { stageA(Sf, kt + 2, 2, 4); stageW(Wr, kt + 2); }
        SBAR;
        WAITLGKM0;
        __builtin_amdgcn_s_setprio(1);
        #pragma unroll
        for (int ri = 0; ri < 4; ++ri)
            #pragma unroll
            for (int ci = 0; ci < 4; ++ci)
                acc[ri][ci] = __builtin_amdgcn_mfma_f32_16x16x32_bf16(w1[ri], s1[ci], acc[ri][ci], 0, 0, 0);
        __builtin_amdgcn_s_setprio(0);
        if (kt < KT - 2) { WAITV6; } else { WAITV0; }   // gate: tile kt+1 landed
        SBAR;
        // rotate ring / swap dbuf
        __hip_bfloat16* tp = Sr; Sr = Sn; Sn = Sf; Sf = tp;
        __hip_bfloat16* tw = Wr; Wr = Wn; Wn = tw;
    }

    // ---------- fused LSTM gate epilogue (identical math to validated rounds) ----------
    const int c0    = (n0 >> 2) + wn * 16;
    const int mcol0 = m0 + wm * 64 + fr;
    __hip_bfloat16* hout = (__hip_bfloat16*)h_pad + (size_t)(b * 8 + t) * FRAME_PAD;
    #pragma unroll
    for (int ri = 0; ri < 4; ++ri) {
        const int c = c0 + ri * 4 + fq;
        const float bi  = bias[c];
        const float bfv = bias[128 + c];
        const float bo  = bias[256 + c];
        const float bg  = bias[384 + c];
        float* csrow = c_state + (size_t)c * 16384;
        #pragma unroll
        for (int ci = 0; ci < 4; ++ci) {
            const int m = mcol0 + ci * 16;
            const int s = m & 4095;
            const float cold = T0 ? 0.0f : csrow[m];
            const float zi = acc[ri][ci][0] + bi;
            const float zf = acc[ri][ci][1] + bfv;
            const float zo = acc[ri][ci][2] + bo;
            const float zg = acc[ri][ci][3] + bg;
            const float cn = sigmoidf_(zf) * cold + sigmoidf_(zi) * tanhf_(zg);
            const float h  = sigmoidf_(zo) * tanhf_(cn);
            csrow[m] = cn;
            hout[(size_t)(((s >> 6) + 1) * 66 + (s & 63) + 1) * 128 + c] = __float2bfloat16(h);
        }
    }
}

// ---------- final: padded-NHWC bf16 h -> NCHW f32 out, BN(eval)+ReLU fused in load ----------
__global__ void bn_out_kernel(const __hip_bfloat16* __restrict__ h_pad,
                              const float* __restrict__ gamma, const float* __restrict__ beta,
                              const float* __restrict__ rmean, const float* __restrict__ rvar,
                              float* __restrict__ out)
{
    __shared__ float tile[64][129];                  // [x][c], post-BN values
    __shared__ float sc_s[128], sh_s[128];
    const int fo  = blockIdx.x >> 6;                 // frame = b*8+t = h slot
    const int y   = blockIdx.x & 63;
    const int tid = threadIdx.x;
    if (tid < 128) {
        float sc = gamma[tid] * rsqrtf(rvar[tid] + 1e-5f);
        sc_s[tid] = sc;
        sh_s[tid] = beta[tid] - rmean[tid] * sc;
    }
    __syncthreads();
    const __hip_bfloat16* src =
        h_pad + (size_t)fo * FRAME_PAD + (size_t)((y + 1) * 66 + 1) * 128;
    const int g = tid & 15;
    float sc[8], sh[8];
    #pragma unroll
    for (int e = 0; e < 8; ++e) { sc[e] = sc_s[g * 8 + e]; sh[e] = sh_s[g * 8 + e]; }
    #pragma unroll
    for (int it = 0; it < 4; ++it) {                 // 64 x-rows x 16 g / 256 thr
        int xr = it * 16 + (tid >> 4);
        bf16x8 v = *(const bf16x8*)(src + (size_t)xr * 128 + g * 8);
        #pragma unroll
        for (int e = 0; e < 8; ++e)
            tile[xr][g * 8 + e] = fmaxf(b2f_(v[e]) * sc[e] + sh[e], 0.0f);
    }
    __syncthreads();
    float* dst = out + (size_t)fo * 524288 + (size_t)y * 64;
    #pragma unroll
    for (int it = 0; it < 8; ++it) {                 // 128 c x 16 xq / 256 thr
        int c  = it * 16 + (tid >> 4);
        int xq = tid & 15;
        float4 o;
        o.x = tile[xq * 4 + 0][c];
        o.y = tile[xq * 4 + 1][c];
        o.z = tile[xq * 4 + 2][c];
        o.w = tile[xq * 4 + 3][c];
        *(float4*)(dst + (size_t)c * 4096 + xq * 4) = o;
    }
}

extern "C" void kernel_launch(void* const* d_in, const int* in_sizes, int n_in,
                              void* d_out, int out_size, void* d_ws, size_t ws_size,
                              hipStream_t stream)
{
    const float* x      = (const float*)d_in[0];
    const float* w_conv = (const float*)d_in[1];
    const float* b_conv = (const float*)d_in[2];
    const float* gamma  = (const float*)d_in[3];
    const float* beta   = (const float*)d_in[4];
    const float* rmean  = (const float*)d_in[5];
    const float* rvar   = (const float*)d_in[6];
    float* out = (float*)d_out;

    // workspace layout (bytes)
    //   Wt      @ 0          : 9*512*256*2    = 2,359,296
    //   x_pad   @ 2359296    : 32*66*66*128*2 = 35,684,352
    //   h_pad   @ 38043648   : 32*66*66*128*2 = 35,684,352   (slot b*8+t = h after step t)
    //   c_state @ 73728000   : 128*16384*4    = 8,388,608    ([c][m]; written before read)
    //   total 82,116,608
    if (ws_size < 82116608u) return;

    char* ws = (char*)d_ws;
    __hip_bfloat16* Wt    = (__hip_bfloat16*)(ws);
    __hip_bfloat16* x_pad = (__hip_bfloat16*)(ws + 2359296);
    __hip_bfloat16* h_pad = (__hip_bfloat16*)(ws + 38043648);
    float* c_state        = (float*)(ws + 73728000);

    wt_kernel<<<4608, 256, 0, stream>>>(w_conv, Wt);
    xpose_kernel<<<2048, 256, 0, stream>>>(x, x_pad);
    border_kernel<<<64, 256, 0, stream>>>(x_pad, h_pad);

    conv_gemm<true><<<256, 512, 0, stream>>>(x_pad, h_pad, Wt, b_conv, c_state, 0);
    for (int t = 1; t < 8; ++t)
        conv_gemm<false><<<256, 512, 0, stream>>>(x_pad, h_pad, Wt, b_conv, c_state, t);

    bn_out_kernel<<<2048, 256, 0, stream>>>(h_pad, gamma, beta, rmean, rvar, out);
}